// Round 7
// baseline (355.974 us; speedup 1.0000x reference)
//
#include <hip/hip_runtime.h>
#include <math.h>

#define T_ 4096
#define NE_ 2048
#define DA_ 2048
#define TDA ((size_t)T_ * NE_)

constexpr int NC = 256;       // time chunks for the WKV scan
constexpr int CL = T_ / NC;   // 16 steps per chunk

typedef __attribute__((ext_vector_type(8))) short short8;
typedef __attribute__((ext_vector_type(4))) float f32x4;

__device__ __forceinline__ unsigned short f2bf(float f) {
  union { float f; unsigned int u; } v; v.f = f;
  unsigned int u = v.u;
  return (unsigned short)((u + 0x7FFFu + ((u >> 16) & 1u)) >> 16);  // RNE
}
__device__ __forceinline__ float bf2f(unsigned short h) {
  union { unsigned int u; float f; } v; v.u = ((unsigned int)h) << 16;
  return v.f;
}

__device__ __forceinline__ void gload_lds16(const void* g, void* l) {
  __builtin_amdgcn_global_load_lds(
      (const __attribute__((address_space(1))) void*)g,
      (__attribute__((address_space(3))) void*)l, 16, 0, 0);
}

// ---------------------------------------------------------------------------
// bf16 MFMA GEMM core, BK=64 (measured r6: 847 TF, MfmaUtil 36.9%, 0 conflicts)
//   C[4096][2048] = A[4096][2048] * Bt[2048][2048]^T      (K = 2048)
// 128x128 tile, 4 waves (2x2), 4x4 x (16x16x32 MFMA) x 2 slices per K-step.
// LDS [128][64] bf16; 8 16B-chunks of each row XOR-swizzled (chunk ^= row&7),
// rule-21 both-sides: pre-swizzled global source + same XOR on ds_read.
// ---------------------------------------------------------------------------
__device__ __forceinline__ void gemm_core(
    const unsigned short* __restrict__ A, const unsigned short* __restrict__ Bt,
    void* __restrict__ C, int c_bf16)
{
  constexpr int K = 2048, N = 2048;
  __shared__ unsigned short As[128 * 64];
  __shared__ unsigned short Bs[128 * 64];

  const int tid = threadIdx.x;
  const int w = tid >> 6, lane = tid & 63;
  const int bm = blockIdx.x * 128, bn = blockIdx.y * 128;
  const int wr = w >> 1, wc = w & 1;

  f32x4 acc[4][4];
#pragma unroll
  for (int m = 0; m < 4; ++m)
#pragma unroll
    for (int n = 0; n < 4; ++n) acc[m][n] = (f32x4){0.f, 0.f, 0.f, 0.f};

  const int sr8 = lane >> 3;
  const int gcs = (lane & 7) ^ sr8;
  const size_t gA0 = (size_t)(bm + w * 32 + sr8) * K + gcs * 8;
  const size_t gB0 = (size_t)(bn + w * 32 + sr8) * K + gcs * 8;
  unsigned short* lA = &As[(w * 32) * 64];   // wave-uniform; HW adds lane*16B
  unsigned short* lB = &Bs[(w * 32) * 64];

  const int lr = lane & 15, ck = lane >> 4;
  const int x7 = lr & 7;
  const int arow = wr * 64 + lr;
  const int brow = wc * 64 + lr;

  for (int kk = 0; kk < K; kk += 64) {
    __syncthreads();                        // previous tile consumed
#pragma unroll
    for (int g = 0; g < 4; ++g) {
      gload_lds16(A + gA0 + kk + (size_t)(g * 8) * K, lA + g * 512);
      gload_lds16(Bt + gB0 + kk + (size_t)(g * 8) * K, lB + g * 512);
    }
    __syncthreads();                        // drains vmcnt -> LDS ready

#pragma unroll
    for (int s = 0; s < 2; ++s) {
      const int c0 = ((s * 4 + ck) ^ x7) * 8;   // swizzled elem offset in row
      short8 af[4], bfr[4];
#pragma unroll
      for (int m = 0; m < 4; ++m)
        af[m] = *reinterpret_cast<const short8*>(&As[(arow + m * 16) * 64 + c0]);
#pragma unroll
      for (int n = 0; n < 4; ++n)
        bfr[n] = *reinterpret_cast<const short8*>(&Bs[(brow + n * 16) * 64 + c0]);
#pragma unroll
      for (int m = 0; m < 4; ++m)
#pragma unroll
        for (int n = 0; n < 4; ++n)
          acc[m][n] = __builtin_amdgcn_mfma_f32_16x16x32_bf16(af[m], bfr[n], acc[m][n], 0, 0, 0);
    }
  }

  // C/D layout (verified m89/m91): col = lane&15, row = (lane>>4)*4 + reg
  const int crow0 = bm + wr * 64 + (lane >> 4) * 4;
  const int ccol0 = bn + wc * 64 + (lane & 15);
  if (c_bf16) {
    unsigned short* Cb = (unsigned short*)C;
#pragma unroll
    for (int m = 0; m < 4; ++m)
#pragma unroll
      for (int n = 0; n < 4; ++n)
#pragma unroll
        for (int j = 0; j < 4; ++j)
          Cb[(size_t)(crow0 + m * 16 + j) * N + ccol0 + n * 16] = f2bf(acc[m][n][j]);
  } else {
    float* Cf = (float*)C;
#pragma unroll
    for (int m = 0; m < 4; ++m)
#pragma unroll
      for (int n = 0; n < 4; ++n)
#pragma unroll
        for (int j = 0; j < 4; ++j)
          Cf[(size_t)(crow0 + m * 16 + j) * N + ccol0 + n * 16] = acc[m][n][j];
  }
}

// z-batched GEMM: blockIdx.z selects (A, Bt, C) triple.
__global__ __launch_bounds__(256) void gemm3_bf16(
    const unsigned short* __restrict__ A0, const unsigned short* __restrict__ A1,
    const unsigned short* __restrict__ A2,
    const unsigned short* __restrict__ B0, const unsigned short* __restrict__ B1,
    const unsigned short* __restrict__ B2,
    void* __restrict__ C0, void* __restrict__ C1, void* __restrict__ C2,
    int c_bf16)
{
  const int z = blockIdx.z;
  const unsigned short* A = (z == 0) ? A0 : (z == 1) ? A1 : A2;
  const unsigned short* B = (z == 0) ? B0 : (z == 1) ? B1 : B2;
  void* C = (z == 0) ? C0 : (z == 1) ? C1 : C2;
  gemm_core(A, B, C, c_bf16);
}

// ---------------------------------------------------------------------------
// z-batched transpose + fp32->bf16, 64x64 tiles, vectorized both sides:
//   O[n][k] = bf16(W[k][n]);  W is [2048][2048]
// load float4 (16B/lane) -> bf16 into LDS transposed -> ushort4 stores
// (16 lanes x 8B = 128B contiguous per row).
// ---------------------------------------------------------------------------
__global__ __launch_bounds__(256) void transpose_cvt3(
    const float* __restrict__ W0, const float* __restrict__ W1,
    const float* __restrict__ W2,
    unsigned short* __restrict__ O0, unsigned short* __restrict__ O1,
    unsigned short* __restrict__ O2)
{
  const int z = blockIdx.z;
  const float* W = (z == 0) ? W0 : (z == 1) ? W1 : W2;
  unsigned short* O = (z == 0) ? O0 : (z == 1) ? O1 : O2;

  __shared__ unsigned short tileT[64][68];   // [n][k], pitch 136B (8B-aligned)
  const int bk = blockIdx.y * 64;   // K block
  const int bn = blockIdx.x * 64;   // N block
  const int u = threadIdx.x;

  {
    const int r = u >> 2;            // K offset 0..63
    const int c0 = (u & 3) * 16;     // N offset
    const float4* src = reinterpret_cast<const float4*>(
        &W[(size_t)(bk + r) * 2048 + bn + c0]);
#pragma unroll
    for (int j = 0; j < 4; ++j) {
      const float4 f = src[j];
      tileT[c0 + j * 4 + 0][r] = f2bf(f.x);
      tileT[c0 + j * 4 + 1][r] = f2bf(f.y);
      tileT[c0 + j * 4 + 2][r] = f2bf(f.z);
      tileT[c0 + j * 4 + 3][r] = f2bf(f.w);
    }
  }
  __syncthreads();
#pragma unroll
  for (int p = 0; p < 4; ++p) {
    const int n = p * 16 + (u >> 4);
    const int k0 = (u & 15) * 4;
    ushort4 o;
    o.x = tileT[n][k0 + 0]; o.y = tileT[n][k0 + 1];
    o.z = tileT[n][k0 + 2]; o.w = tileT[n][k0 + 3];
    *reinterpret_cast<ushort4*>(&O[(size_t)(bn + n) * 2048 + bk + k0]) = o;
  }
}

// ---------------------------------------------------------------------------
// Fused triple time-mix + fp32->bf16 (reads x once)
// ---------------------------------------------------------------------------
__global__ __launch_bounds__(256) void mix3_cvt(
    const float* __restrict__ x,
    const float* __restrict__ tmk, const float* __restrict__ tmv,
    const float* __restrict__ tmr,
    unsigned short* __restrict__ ok, unsigned short* __restrict__ ov,
    unsigned short* __restrict__ orr)
{
  const int i = blockIdx.x * 256 + threadIdx.x;   // float4 index
  const int t = i / (NE_ / 4);
  const int e4 = i % (NE_ / 4);
  const float4 xc = reinterpret_cast<const float4*>(x)[i];
  float4 xp = make_float4(0.f, 0.f, 0.f, 0.f);
  if (t > 0) xp = reinterpret_cast<const float4*>(x)[i - NE_ / 4];
  const float4 dx = make_float4(xc.x - xp.x, xc.y - xp.y, xc.z - xp.z, xc.w - xp.w);

  float4 m;
  ushort4 r;
  m = reinterpret_cast<const float4*>(tmk)[e4];
  r.x = f2bf(xp.x + m.x * dx.x); r.y = f2bf(xp.y + m.y * dx.y);
  r.z = f2bf(xp.z + m.z * dx.z); r.w = f2bf(xp.w + m.w * dx.w);
  reinterpret_cast<ushort4*>(ok)[i] = r;
  m = reinterpret_cast<const float4*>(tmv)[e4];
  r.x = f2bf(xp.x + m.x * dx.x); r.y = f2bf(xp.y + m.y * dx.y);
  r.z = f2bf(xp.z + m.z * dx.z); r.w = f2bf(xp.w + m.w * dx.w);
  reinterpret_cast<ushort4*>(ov)[i] = r;
  m = reinterpret_cast<const float4*>(tmr)[e4];
  r.x = f2bf(xp.x + m.x * dx.x); r.y = f2bf(xp.y + m.y * dx.y);
  r.z = f2bf(xp.z + m.z * dx.z); r.w = f2bf(xp.w + m.w * dx.w);
  reinterpret_cast<ushort4*>(orr)[i] = r;
}

// ---------------------------------------------------------------------------
// WKV chunked linear scan, bf16 k/v, 4 channels per thread.
//   P_t = lam*P + e^{k_t} v_t ,  Q_t = lam*Q + e^{k_t}
//   y_t = (P_{t-1} + e^{u+k_t} v_t) / (Q_{t-1} + e^{u+k_t})
// 256-thread blocks, grid (2, NC=256) = 512 blocks (8 waves/CU); CL=16 with
// deep unroll so the load stream runs ahead of the serial P/Q chain.
// ---------------------------------------------------------------------------
__global__ __launch_bounds__(256) void wkv_pass1(
    const unsigned short* __restrict__ Kb, const unsigned short* __restrict__ Vb,
    const float* __restrict__ td, float* __restrict__ SP, float* __restrict__ SQ)
{
  const int c4 = blockIdx.x * 256 + threadIdx.x;   // 4-channel group
  const int chunk = blockIdx.y;
  const int t0 = chunk * CL;
  const float4 tdv = reinterpret_cast<const float4*>(td)[c4];
  float lam[4] = {__expf(-__expf(tdv.x)), __expf(-__expf(tdv.y)),
                  __expf(-__expf(tdv.z)), __expf(-__expf(tdv.w))};
  float P[4] = {0.f, 0.f, 0.f, 0.f}, Q[4] = {0.f, 0.f, 0.f, 0.f};
#pragma unroll 8
  for (int t = t0; t < t0 + CL; ++t) {
    const ushort4 kq = reinterpret_cast<const ushort4*>(Kb + (size_t)t * DA_)[c4];
    const ushort4 vq = reinterpret_cast<const ushort4*>(Vb + (size_t)t * DA_)[c4];
    const float kf[4] = {bf2f(kq.x), bf2f(kq.y), bf2f(kq.z), bf2f(kq.w)};
    const float vf[4] = {bf2f(vq.x), bf2f(vq.y), bf2f(vq.z), bf2f(vq.w)};
#pragma unroll
    for (int j = 0; j < 4; ++j) {
      const float e = __expf(kf[j]);
      P[j] = fmaf(lam[j], P[j], e * vf[j]);
      Q[j] = fmaf(lam[j], Q[j], e);
    }
  }
  reinterpret_cast<float4*>(SP + (size_t)chunk * DA_)[c4] = (float4){P[0], P[1], P[2], P[3]};
  reinterpret_cast<float4*>(SQ + (size_t)chunk * DA_)[c4] = (float4){Q[0], Q[1], Q[2], Q[3]};
}

// per-channel exclusive scan over NC chunk-sums; tiles of 16 independent loads
__global__ __launch_bounds__(256) void wkv_pass2(
    const float* __restrict__ td, float* __restrict__ SP, float* __restrict__ SQ)
{
  const int c = blockIdx.x * 256 + threadIdx.x;   // one channel per thread
  const float lamL = __expf(-__expf(td[c]) * (float)CL);  // lam^CL
  float P = 0.f, Q = 0.f;
  for (int i0 = 0; i0 < NC; i0 += 16) {
    float sp[16], sq[16];
#pragma unroll
    for (int j = 0; j < 16; ++j) {
      sp[j] = SP[(size_t)(i0 + j) * DA_ + c];
      sq[j] = SQ[(size_t)(i0 + j) * DA_ + c];
    }
#pragma unroll
    for (int j = 0; j < 16; ++j) {
      SP[(size_t)(i0 + j) * DA_ + c] = P;   // exclusive prefix
      SQ[(size_t)(i0 + j) * DA_ + c] = Q;
      P = fmaf(lamL, P, sp[j]);
      Q = fmaf(lamL, Q, sq[j]);
    }
  }
}

__global__ __launch_bounds__(256) void wkv_pass3(
    const unsigned short* __restrict__ Kb, const unsigned short* __restrict__ Vb,
    const unsigned short* __restrict__ Rb, unsigned short* __restrict__ Ab,
    const float* __restrict__ td, const float* __restrict__ tf,
    const float* __restrict__ SP, const float* __restrict__ SQ)
{
  const int c4 = blockIdx.x * 256 + threadIdx.x;
  const int chunk = blockIdx.y;
  const int t0 = chunk * CL;
  const float4 tdv = reinterpret_cast<const float4*>(td)[c4];
  const float4 tfv = reinterpret_cast<const float4*>(tf)[c4];
  const float lam[4] = {__expf(-__expf(tdv.x)), __expf(-__expf(tdv.y)),
                        __expf(-__expf(tdv.z)), __expf(-__expf(tdv.w))};
  const float eu[4] = {__expf(tfv.x), __expf(tfv.y), __expf(tfv.z), __expf(tfv.w)};
  const float4 p0 = reinterpret_cast<const float4*>(SP + (size_t)chunk * DA_)[c4];
  const float4 q0 = reinterpret_cast<const float4*>(SQ + (size_t)chunk * DA_)[c4];
  float P[4] = {p0.x, p0.y, p0.z, p0.w};
  float Q[4] = {q0.x, q0.y, q0.z, q0.w};
#pragma unroll 4
  for (int t = t0; t < t0 + CL; ++t) {
    const ushort4 kq = reinterpret_cast<const ushort4*>(Kb + (size_t)t * DA_)[c4];
    const ushort4 vq = reinterpret_cast<const ushort4*>(Vb + (size_t)t * DA_)[c4];
    const ushort4 rq = reinterpret_cast<const ushort4*>(Rb + (size_t)t * DA_)[c4];
    const float kf[4] = {bf2f(kq.x), bf2f(kq.y), bf2f(kq.z), bf2f(kq.w)};
    const float vf[4] = {bf2f(vq.x), bf2f(vq.y), bf2f(vq.z), bf2f(vq.w)};
    const float rf[4] = {bf2f(rq.x), bf2f(rq.y), bf2f(rq.z), bf2f(rq.w)};
    ushort4 a;
    unsigned short* ap = (unsigned short*)&a;
#pragma unroll
    for (int j = 0; j < 4; ++j) {
      const float e = __expf(kf[j]);
      const float b = eu[j] * e;
      const float y = (P[j] + b * vf[j]) / (Q[j] + b);
      const float sr = 1.f / (1.f + __expf(-rf[j]));
      ap[j] = f2bf(sr * y);
      P[j] = fmaf(lam[j], P[j], e * vf[j]);
      Q[j] = fmaf(lam[j], Q[j], e);
    }
    reinterpret_cast<ushort4*>(Ab + (size_t)t * DA_)[c4] = a;
  }
}

// ---------------------------------------------------------------------------
extern "C" void kernel_launch(void* const* d_in, const int* in_sizes, int n_in,
                              void* d_out, int out_size, void* d_ws, size_t ws_size,
                              hipStream_t stream)
{
  const float* x   = (const float*)d_in[0];
  const float* tf  = (const float*)d_in[1];
  const float* td  = (const float*)d_in[2];
  const float* tmk = (const float*)d_in[3];
  const float* tmv = (const float*)d_in[4];
  const float* tmr = (const float*)d_in[5];
  const float* Wk  = (const float*)d_in[6];  // [NE, DA]
  const float* Wv  = (const float*)d_in[7];
  const float* Wr  = (const float*)d_in[8];
  const float* Wo  = (const float*)d_in[9];  // [DA, NE]
  float* out = (float*)d_out;

  const size_t MB = 1024 * 1024;
  char* ws = (char*)d_ws;

  const dim3 blk(256);
  const dim3 tgrid3(32, 32, 3), tgrid1(32, 32, 1);   // 64x64 tiles
  const dim3 ggrid1(T_ / 128, DA_ / 128, 1);
  const dim3 wgrid(DA_ / 4 / 256, NC);               // (2, 256)
  const size_t NEED_BATCH = 120 * MB;

  if (ws_size >= NEED_BATCH) {
    // ---- batched layout (120 MB) ----
    unsigned short* xmk = (unsigned short*)(ws + 0 * MB);    // 16 MB; reused as `a`
    unsigned short* xmv = (unsigned short*)(ws + 16 * MB);
    unsigned short* xmr = (unsigned short*)(ws + 32 * MB);
    unsigned short* WtK = (unsigned short*)(ws + 48 * MB);   // 8 MB; reused as WoT
    unsigned short* WtV = (unsigned short*)(ws + 56 * MB);   // slot reused as sp/sq
    unsigned short* WtR = (unsigned short*)(ws + 64 * MB);
    unsigned short* kb  = (unsigned short*)(ws + 72 * MB);   // 16 MB bf16
    unsigned short* vb  = (unsigned short*)(ws + 88 * MB);
    unsigned short* rb  = (unsigned short*)(ws + 104 * MB);
    // sp/sq (2 MB each, NC=256) overlay WtV's slot — WtV dead after gemm3
    float* sp = (float*)(ws + 56 * MB);
    float* sq = (float*)(ws + 58 * MB);

    transpose_cvt3<<<tgrid3, blk, 0, stream>>>(Wk, Wv, Wr, WtK, WtV, WtR);
    mix3_cvt<<<TDA / 4 / 256, blk, 0, stream>>>(x, tmk, tmv, tmr, xmk, xmv, xmr);
    gemm3_bf16<<<dim3(T_ / 128, DA_ / 128, 3), blk, 0, stream>>>(
        xmk, xmv, xmr, WtK, WtV, WtR, kb, vb, rb, 1);

    // Wo transpose: WtK is dead after gemm3
    transpose_cvt3<<<tgrid1, blk, 0, stream>>>(Wo, Wo, Wo, WtK, WtK, WtK);

    wkv_pass1<<<wgrid, blk, 0, stream>>>(kb, vb, td, sp, sq);
    wkv_pass2<<<dim3(DA_ / 256), blk, 0, stream>>>(td, sp, sq);
    wkv_pass3<<<wgrid, blk, 0, stream>>>(kb, vb, rb, xmk, td, tf, sp, sq);

    gemm3_bf16<<<ggrid1, blk, 0, stream>>>(xmk, xmk, xmk, WtK, WtK, WtK, out, out, out, 0);
  } else {
    // ---- sequential fallback (110 MB) ----
    unsigned short* xmk = (unsigned short*)(ws + 0 * MB);
    unsigned short* xmv = (unsigned short*)(ws + 16 * MB);
    unsigned short* xmr = (unsigned short*)(ws + 32 * MB);
    unsigned short* Wt  = (unsigned short*)(ws + 48 * MB);   // single, reused 4x
    unsigned short* kb  = (unsigned short*)(ws + 56 * MB);
    unsigned short* vb  = (unsigned short*)(ws + 72 * MB);
    unsigned short* rb  = (unsigned short*)(ws + 88 * MB);
    float* sp = (float*)(ws + 104 * MB);
    float* sq = (float*)(ws + 106 * MB);

    mix3_cvt<<<TDA / 4 / 256, blk, 0, stream>>>(x, tmk, tmv, tmr, xmk, xmv, xmr);
    transpose_cvt3<<<tgrid1, blk, 0, stream>>>(Wk, Wk, Wk, Wt, Wt, Wt);
    gemm3_bf16<<<ggrid1, blk, 0, stream>>>(xmk, xmk, xmk, Wt, Wt, Wt, kb, kb, kb, 1);
    transpose_cvt3<<<tgrid1, blk, 0, stream>>>(Wv, Wv, Wv, Wt, Wt, Wt);
    gemm3_bf16<<<ggrid1, blk, 0, stream>>>(xmv, xmv, xmv, Wt, Wt, Wt, vb, vb, vb, 1);
    transpose_cvt3<<<tgrid1, blk, 0, stream>>>(Wr, Wr, Wr, Wt, Wt, Wt);
    gemm3_bf16<<<ggrid1, blk, 0, stream>>>(xmr, xmr, xmr, Wt, Wt, Wt, rb, rb, rb, 1);

    wkv_pass1<<<wgrid, blk, 0, stream>>>(kb, vb, td, sp, sq);
    wkv_pass2<<<dim3(DA_ / 256), blk, 0, stream>>>(td, sp, sq);
    wkv_pass3<<<wgrid, blk, 0, stream>>>(kb, vb, rb, xmk, td, tf, sp, sq);

    transpose_cvt3<<<tgrid1, blk, 0, stream>>>(Wo, Wo, Wo, Wt, Wt, Wt);
    gemm3_bf16<<<ggrid1, blk, 0, stream>>>(xmk, xmk, xmk, Wt, Wt, Wt, out, out, out, 0);
  }
}